// Round 10
// baseline (164.779 us; speedup 1.0000x reference)
//
#include <hip/hip_runtime.h>
#include <stdint.h>

typedef __attribute__((ext_vector_type(8))) short short8;
typedef __attribute__((ext_vector_type(4))) float f32x4;
typedef __attribute__((ext_vector_type(8))) float f32x8;
typedef __attribute__((ext_vector_type(16))) float f32x16;
typedef __bf16 bf16x8_t __attribute__((ext_vector_type(8)));

#define NN 784              // 28*28
#define NA 28               // output rows a
#define ABYTES 16384        // W bytes per a: 16 K-steps x 1KB frag

__device__ __forceinline__ unsigned short f2bf(float f) {
  unsigned int u = __float_as_uint(f);
  return (unsigned short)((u + 0x7FFFu + ((u >> 16) & 1u)) >> 16);  // RNE, finite
}

__device__ __forceinline__ short8 cvt8(f32x4 lo, f32x4 hi) {
  f32x8 f = {lo.x, lo.y, lo.z, lo.w, hi.x, hi.y, hi.z, hi.w};
  bf16x8_t b = __builtin_convertvector(f, bf16x8_t);   // v_cvt_pk_bf16_f32 (RNE)
  return __builtin_bit_cast(short8, b);
}

// First k-slot (32-wide) of output row a's 256-wide window covering 28(a-3)..28(a+4).
__host__ __device__ constexpr int slot0c(int a) {
  int t = 28 * a - 84;
  if (t < 0) t = 0;
  t >>= 5;
  if (t > 17) t = 17;
  return t;
}
// x sliding-ring schedule (2-iteration prefetch): target slot after iter I.
__host__ __device__ constexpr int tgtc(int I) { int a2 = I + 2 > 27 ? 27 : I + 2; return slot0c(a2) + 7; }
__host__ __device__ constexpr bool xissue(int I) { return I >= 1 && tgtc(I) > tgtc(I - 1); }
__host__ __device__ constexpr bool xcvt(int A)   { return A >= 3 && xissue(A - 2); }   // cvt slot == slot0c(A)+7

// Bpack[a][step 0..15] = 1KB A-fragment for mfma_f32_32x32x16_bf16:
// A[row=outcol][k]: u16 idx = lane*8 + j, lane = (k>>3)*32 + outcol, j = k&7.
// Value = weight[a*28+outcol] * W[a*28+outcol][kglob], 0 outside grid/band.
__global__ void build_w_kernel(const float* __restrict__ pos2d,
                               const float* __restrict__ weight,
                               const float* __restrict__ ep,
                               unsigned short* __restrict__ Bpack) {
  int idx = blockIdx.x * 256 + threadIdx.x;   // 0 .. 28*16*512-1
  int u    = idx & 511;
  int frag = idx >> 9;           // a*16 + s2
  int s2 = frag & 15;
  int a  = frag >> 4;
  int j    = u & 7;
  int lane = u >> 3;
  int outcol = lane & 31;
  int kh     = lane >> 5;
  int kk = kh * 8 + j;                         // k within K16 step
  int kglob = slot0c(a) * 32 + s2 * 16 + kk;
  float val = 0.f;
  if (outcol < 28 && kglob < NN) {
    float px = pos2d[2 * kglob + 0];
    float py = pos2d[2 * kglob + 1];
    float dx = (float)outcol - px;
    float dy = (float)a - py;
    float d2 = __fadd_rn(__fmul_rn(dx, dx), __fmul_rn(dy, dy));  // match np (no fma)
    if (d2 < 9.0f) {
      float en = fminf(ep[kglob], 0.f);
      val = expf(en * d2) * weight[a * 28 + outcol];
    }
  }
  Bpack[idx] = f2bf(val);
}

// One fully-unrolled a-iteration (A compile-time => all ring indices static).
template <int A>
struct It {
  static __device__ __forceinline__ void run(
      const float* __restrict__ xrow, const char* __restrict__ wb,
      float* __restrict__ orow, int kh,
      short8 (&rlo)[10], short8 (&rhi)[10],
      short8 (&wfA)[8], short8 (&wfB)[8], f32x4 (&stg)[2][4]) {
    constexpr int T0 = slot0c(A);

    // 1) convert slot staged 2 iterations ago (just-in-time for this window)
    if constexpr (xcvt(A)) {
      constexpr int S = slot0c(A) + 7;
      rlo[S % 10] = cvt8(stg[A & 1][0], stg[A & 1][1]);
      if constexpr (S < 24) rhi[S % 10] = cvt8(stg[A & 1][2], stg[A & 1][3]);
      else                  rhi[S % 10] = short8{};      // k>=784 pad (W pad is 0 too)
    }
    // 2) issue x loads for the slot needed at iteration A+2
    if constexpr (xissue(A)) {
      constexpr int S = tgtc(A);
      const float* p = xrow + S * 32 + kh * 8;
      stg[A & 1][0] = *(const f32x4*)p;
      stg[A & 1][1] = *(const f32x4*)(p + 4);
      if constexpr (S < 24) {
        stg[A & 1][2] = *(const f32x4*)(p + 16);
        stg[A & 1][3] = *(const f32x4*)(p + 20);
      }
    }
    // 3) issue W frags 8..15 of a=A (used in second half of this iter)
    #pragma unroll
    for (int f = 0; f < 8; ++f)
      wfA[f] = *(const short8*)(wb + A * ABYTES + (8 + f) * 1024);

    f32x16 acc = {};

#define KSTEP(s, wf) { constexpr int SL = (T0 + ((s) >> 1)) % 10;               \
    acc = __builtin_amdgcn_mfma_f32_32x32x16_bf16(                              \
        wf, ((s) & 1) ? rhi[SL] : rlo[SL], acc, 0, 0, 0); }

    // 4) first half: K-steps 0..7 with wfB (loaded during previous iteration)
    KSTEP(0, wfB[0]) KSTEP(1, wfB[1]) KSTEP(2, wfB[2]) KSTEP(3, wfB[3])
    KSTEP(4, wfB[4]) KSTEP(5, wfB[5]) KSTEP(6, wfB[6]) KSTEP(7, wfB[7])

    // 5) issue W frags 0..7 of a=A+1
    if constexpr (A + 1 < NA) {
      #pragma unroll
      for (int f = 0; f < 8; ++f)
        wfB[f] = *(const short8*)(wb + (A + 1) * ABYTES + f * 1024);
    }

    // 6) second half: K-steps 8..15 with wfA
    KSTEP(8,  wfA[0]) KSTEP(9,  wfA[1]) KSTEP(10, wfA[2]) KSTEP(11, wfA[3])
    KSTEP(12, wfA[4]) KSTEP(13, wfA[5]) KSTEP(14, wfA[6]) KSTEP(15, wfA[7])
#undef KSTEP

    // 7) stores: C'[outcol,img]: lane=img, reg quad g -> outcols 8g+4kh..+3
    #pragma unroll
    for (int g = 0; g < 4; ++g) {
      if (g < 3 || kh == 0) {                 // outcol >= 28 skipped
        f32x4 v = {acc[4 * g + 0], acc[4 * g + 1], acc[4 * g + 2], acc[4 * g + 3]};
        *(f32x4*)(orow + A * 28 + 8 * g + 4 * kh) = v;   // 16B aligned
      }
    }

    It<A + 1>::run(xrow, wb, orow, kh, rlo, rhi, wfA, wfB, stg);
  }
};
template <>
struct It<NA> {
  static __device__ __forceinline__ void run(const float*, const char*, float*, int,
                                             short8 (&)[10], short8 (&)[10],
                                             short8 (&)[8], short8 (&)[8], f32x4 (&)[2][4]) {}
};

// Zero-LDS, zero-barrier banded GEMM. Block = 4 waves x 32 images (512 blocks,
// all resident). Per wave: x row window in a register ring (bf16, statically
// indexed), W fragments stream L2->registers double-buffered, 16 MFMA
// (32x32x16, W as A-operand) per output row a, contiguous-ish dwordx4 stores.
// All waits are compiler-counted vmcnt on register deps.
__global__ __launch_bounds__(256, 2)
void gemm_kernel(const float* __restrict__ x,
                 const unsigned short* __restrict__ Bpack,
                 float* __restrict__ out) {
  const int wave = threadIdx.x >> 6;
  const int lane = threadIdx.x & 63;
  const int img  = lane & 31;
  const int kh   = lane >> 5;
  const int m0   = blockIdx.x * 128 + wave * 32;

  const float* xrow = x + (size_t)(m0 + img) * NN;
  float*       orow = out + (size_t)(m0 + img) * NN;
  const char*  wb   = (const char*)Bpack + lane * 16;

  short8 rlo[10], rhi[10];
  short8 wfA[8], wfB[8];
  f32x4  stg[2][4];

  // W prologue: a=0, frags 0..7
  #pragma unroll
  for (int f = 0; f < 8; ++f)
    wfB[f] = *(const short8*)(wb + f * 1024);

  // x prologue: slots 0..7 (k = 0..255, all in range)
#define PRO(S) { const float* p = xrow + (S) * 32 + kh * 8;                     \
    f32x4 a0 = *(const f32x4*)p,        a1 = *(const f32x4*)(p + 4);            \
    f32x4 b0 = *(const f32x4*)(p + 16), b1 = *(const f32x4*)(p + 20);           \
    rlo[S] = cvt8(a0, a1); rhi[S] = cvt8(b0, b1); }
  PRO(0) PRO(1) PRO(2) PRO(3) PRO(4) PRO(5) PRO(6) PRO(7)
#undef PRO

  It<0>::run(xrow, wb, orow, kh, rlo, rhi, wfA, wfB, stg);
}

extern "C" void kernel_launch(void* const* d_in, const int* in_sizes, int n_in,
                              void* d_out, int out_size, void* d_ws, size_t ws_size,
                              hipStream_t stream) {
  const float* x      = (const float*)d_in[0];
  const float* pos2d  = (const float*)d_in[1];
  const float* weight = (const float*)d_in[2];
  const float* ep     = (const float*)d_in[3];
  float* out          = (float*)d_out;
  unsigned short* Bpack = (unsigned short*)d_ws;        // 28*16*512*2 = 458,752 B

  int batch = in_sizes[0] / NN;                         // 65536

  build_w_kernel<<<dim3((NA * 16 * 512) / 256), dim3(256), 0, stream>>>(
      pos2d, weight, ep, Bpack);
  gemm_kernel<<<dim3(batch / 128), dim3(256), 0, stream>>>(x, Bpack, out);
}

// Round 11
// 124.385 us; speedup vs baseline: 1.3247x; 1.3247x over previous
//
#include <hip/hip_runtime.h>
#include <stdint.h>

typedef __attribute__((ext_vector_type(8))) short short8;
typedef __attribute__((ext_vector_type(4))) float f32x4;
typedef __attribute__((ext_vector_type(8))) float f32x8;
typedef __attribute__((ext_vector_type(16))) float f32x16;
typedef __attribute__((ext_vector_type(2))) float f32x2;
typedef __bf16 bf16x8_t __attribute__((ext_vector_type(8)));

#define NN 784              // 28*28
#define NA 28               // output rows a
#define ABYTES 16384        // W bytes per a: 16 K-steps x 1KB frag
#define NIMG 128            // images per block (4 waves x 32)
#define OROW 232            // padded olds row bytes (56 cols used = 224)

__device__ __forceinline__ unsigned short f2bf(float f) {
  unsigned int u = __float_as_uint(f);
  return (unsigned short)((u + 0x7FFFu + ((u >> 16) & 1u)) >> 16);  // RNE, finite
}

__device__ __forceinline__ short8 cvt8(f32x4 lo, f32x4 hi) {
  f32x8 f = {lo.x, lo.y, lo.z, lo.w, hi.x, hi.y, hi.z, hi.w};
  bf16x8_t b = __builtin_convertvector(f, bf16x8_t);   // v_cvt_pk_bf16_f32 (RNE)
  return __builtin_bit_cast(short8, b);
}

// First k-slot (32-wide) of output row a's 256-wide window covering 28(a-3)..28(a+4).
__host__ __device__ constexpr int slot0c(int a) {
  int t = 28 * a - 84;
  if (t < 0) t = 0;
  t >>= 5;
  if (t > 17) t = 17;
  return t;
}
// x sliding-ring schedule (2-iteration prefetch): target slot after iter I.
__host__ __device__ constexpr int tgtc(int I) { int a2 = I + 2 > 27 ? 27 : I + 2; return slot0c(a2) + 7; }
__host__ __device__ constexpr bool xissue(int I) { return I >= 1 && tgtc(I) > tgtc(I - 1); }
__host__ __device__ constexpr bool xcvt(int A)   { return A >= 3 && xissue(A - 2); }

// Bpack[a][step 0..15] = 1KB A-fragment for mfma_f32_32x32x16_bf16 (same as R10).
__global__ void build_w_kernel(const float* __restrict__ pos2d,
                               const float* __restrict__ weight,
                               const float* __restrict__ ep,
                               unsigned short* __restrict__ Bpack) {
  int idx = blockIdx.x * 256 + threadIdx.x;   // 0 .. 28*16*512-1
  int u    = idx & 511;
  int frag = idx >> 9;           // a*16 + s2
  int s2 = frag & 15;
  int a  = frag >> 4;
  int j    = u & 7;
  int lane = u >> 3;
  int outcol = lane & 31;
  int kh     = lane >> 5;
  int kk = kh * 8 + j;
  int kglob = slot0c(a) * 32 + s2 * 16 + kk;
  float val = 0.f;
  if (outcol < 28 && kglob < NN) {
    float px = pos2d[2 * kglob + 0];
    float py = pos2d[2 * kglob + 1];
    float dx = (float)outcol - px;
    float dy = (float)a - py;
    float d2 = __fadd_rn(__fmul_rn(dx, dx), __fmul_rn(dy, dy));  // match np (no fma)
    if (d2 < 9.0f) {
      float en = fminf(ep[kglob], 0.f);
      val = expf(en * d2) * weight[a * 28 + outcol];
    }
  }
  Bpack[idx] = f2bf(val);
}

// One fully-unrolled a-iteration.
template <int A>
struct It {
  static __device__ __forceinline__ void run(
      const float* __restrict__ xrow, const unsigned short* __restrict__ Bpack,
      char* __restrict__ wlds, char* __restrict__ olds,
      float* __restrict__ oblk, int tid, int lane,
      short8 (&rlo)[10], short8 (&rhi)[10], f32x4 (&stg)[2][4]) {
    constexpr int T0 = slot0c(A);
    const int il = lane & 31;
    const int kh = lane >> 5;

    // 1) issue W stage loads for a=A+1 (coalesced: 64B/thread, block covers 16KB)
    f32x4 sr[4];
    if constexpr (A + 1 < NA) {
      const char* src = (const char*)Bpack + (A + 1) * ABYTES + tid * 16;
      #pragma unroll
      for (int r = 0; r < 4; ++r)
        sr[r] = *(const f32x4*)(src + r * 4096);
    }

    // 2) convert x slot staged 2 iterations ago
    if constexpr (xcvt(A)) {
      constexpr int S = slot0c(A) + 7;
      rlo[S % 10] = cvt8(stg[A & 1][0], stg[A & 1][1]);
      if constexpr (S < 24) rhi[S % 10] = cvt8(stg[A & 1][2], stg[A & 1][3]);
      else                  rhi[S % 10] = short8{};      // k>=784 pad (W pad 0 too)
    }
    // 3) issue x loads for the slot needed at iteration A+2
    if constexpr (xissue(A)) {
      constexpr int S = tgtc(A);
      const float* p = xrow + S * 32 + kh * 8;
      stg[A & 1][0] = *(const f32x4*)p;
      stg[A & 1][1] = *(const f32x4*)(p + 4);
      if constexpr (S < 24) {
        stg[A & 1][2] = *(const f32x4*)(p + 16);
        stg[A & 1][3] = *(const f32x4*)(p + 20);
      }
    }

    // 4) compute a=A from LDS ring buf A%3 (16 frag reads + 16 MFMA)
    const char* wbuf = wlds + (A % 3) * ABYTES + lane * 16;
    f32x16 acc = {};
#define KSTEP(s) { constexpr int SL = (T0 + ((s) >> 1)) % 10;                   \
    short8 wf = *(const short8*)(wbuf + (s) * 1024);                            \
    acc = __builtin_amdgcn_mfma_f32_32x32x16_bf16(                              \
        wf, ((s) & 1) ? rhi[SL] : rlo[SL], acc, 0, 0, 0); }
    KSTEP(0)  KSTEP(1)  KSTEP(2)  KSTEP(3)
    KSTEP(4)  KSTEP(5)  KSTEP(6)  KSTEP(7)
    KSTEP(8)  KSTEP(9)  KSTEP(10) KSTEP(11)
    KSTEP(12) KSTEP(13) KSTEP(14) KSTEP(15)
#undef KSTEP

    // 5) write staged W to ring buf (A+1)%3 (compiler waits exactly on sr loads)
    if constexpr (A + 1 < NA) {
      char* dst = wlds + ((A + 1) % 3) * ABYTES + tid * 16;
      #pragma unroll
      for (int r = 0; r < 4; ++r)
        *(f32x4*)(dst + r * 4096) = sr[r];
    }

    // 6) acc -> olds out-tile: img = (wave*32+il), pair-col = (A&1)*28 + 8g+4kh
    {
      char* obase = olds + (tid >> 6) * 32 * OROW + il * OROW + ((A & 1) * 28 + 4 * kh) * 4;
      #pragma unroll
      for (int g = 0; g < 4; ++g) {
        if (g < 3 || kh == 0) {                    // outcol 8g+4kh < 28
          f32x2 v0 = {acc[4 * g + 0], acc[4 * g + 1]};
          f32x2 v1 = {acc[4 * g + 2], acc[4 * g + 3]};
          *(f32x2*)(obase + g * 32) = v0;          // ds_write_b64, 8B aligned
          *(f32x2*)(obase + g * 32 + 8) = v1;
        }
      }
    }

    __builtin_amdgcn_s_barrier();                  // ring(A+1) ready, acc visible

    // 7) every odd A: flush pair p = A/2 (224B contiguous per image row)
    if constexpr (A & 1) {
      constexpr int P = A >> 1;
      #pragma unroll
      for (int r = 0; r < 14; ++r) {
        int e = r * 256 + tid;                     // 14*256 = 128*28 exactly
        int img = e / 28, u = e - img * 28;
        f32x2 v = *(const f32x2*)(olds + img * OROW + u * 8);
        *(f32x2*)((char*)(oblk + (size_t)img * NN + P * 56) + u * 8) = v;
      }
      __builtin_amdgcn_s_barrier();                // flush reads done before reuse
    }

    It<A + 1>::run(xrow, Bpack, wlds, olds, oblk, tid, lane, rlo, rhi, stg);
  }
};
template <>
struct It<NA> {
  static __device__ __forceinline__ void run(const float*, const unsigned short*,
                                             char*, char*, float*, int, int,
                                             short8 (&)[10], short8 (&)[10],
                                             f32x4 (&)[2][4]) {}
};

// Banded GEMM, line-traffic-minimized. Block = 4 waves x 32 img = 128 images.
// W(a) 16KB staged once per block per a (reg-bounced ring-3, coalesced);
// x per-lane register ring (R10 schedule); acc -> LDS out-tile; flush every
// two a's as contiguous 224B-per-image runs. One barrier/iter (+1 on odd).
__global__ __launch_bounds__(256, 2)
void gemm_kernel(const float* __restrict__ x,
                 const unsigned short* __restrict__ Bpack,
                 float* __restrict__ out) {
  __shared__ char wlds[3 * ABYTES];        // 48 KB W ring
  __shared__ char olds[NIMG * OROW];       // 29696 B out-tile

  const int tid  = threadIdx.x;
  const int wave = tid >> 6;
  const int lane = tid & 63;
  const int il   = lane & 31;
  const int kh   = lane >> 5;
  const int m0   = blockIdx.x * NIMG + wave * 32;

  const float* xrow = x + (size_t)(m0 + il) * NN;
  float*       oblk = out + (size_t)(blockIdx.x * NIMG) * NN;

  short8 rlo[10], rhi[10];
  f32x4  stg[2][4];

  // W prologue: stage a=0 into ring buf 0
  {
    const char* src = (const char*)Bpack + tid * 16;
    #pragma unroll
    for (int r = 0; r < 4; ++r) {
      f32x4 v = *(const f32x4*)(src + r * 4096);
      *(f32x4*)(wlds + tid * 16 + r * 4096) = v;
    }
  }

  // x prologue: slots 0..7 (k = 0..255, in range)
#define PRO(S) { const float* p = xrow + (S) * 32 + kh * 8;                     \
    f32x4 a0 = *(const f32x4*)p,        a1 = *(const f32x4*)(p + 4);            \
    f32x4 b0 = *(const f32x4*)(p + 16), b1 = *(const f32x4*)(p + 20);           \
    rlo[S] = cvt8(a0, a1); rhi[S] = cvt8(b0, b1); }
  PRO(0) PRO(1) PRO(2) PRO(3) PRO(4) PRO(5) PRO(6) PRO(7)
#undef PRO

  __syncthreads();                         // ring buf 0 ready

  It<0>::run(xrow, Bpack, wlds, olds, oblk, tid, lane, rlo, rhi, stg);
}

extern "C" void kernel_launch(void* const* d_in, const int* in_sizes, int n_in,
                              void* d_out, int out_size, void* d_ws, size_t ws_size,
                              hipStream_t stream) {
  const float* x      = (const float*)d_in[0];
  const float* pos2d  = (const float*)d_in[1];
  const float* weight = (const float*)d_in[2];
  const float* ep     = (const float*)d_in[3];
  float* out          = (float*)d_out;
  unsigned short* Bpack = (unsigned short*)d_ws;        // 28*16*512*2 = 458,752 B

  int batch = in_sizes[0] / NN;                         // 65536

  build_w_kernel<<<dim3((NA * 16 * 512) / 256), dim3(256), 0, stream>>>(
      pos2d, weight, ep, Bpack);
  gemm_kernel<<<dim3(batch / NIMG), dim3(256), 0, stream>>>(x, Bpack, out);
}